// Round 1
// baseline (2795.363 us; speedup 1.0000x reference)
//
#include <hip/hip_runtime.h>
#include <math.h>

// Problem constants
#define B_    8
#define T_    12
#define BT    96          // B*T
#define NN    500
#define DD    512
#define KK    1024        // 2*D
#define SK    35          // SAMPLE_K == n_top
#define MROWS 48000       // BT*NN

// ---------------------------------------------------------------------------
// K1: out[r,j] = relu(bias[j] + sum_i Xc[r,i]*W[i,j]),  Xc = [X | STE]
// M=48000, K=1024, N=512.  BM=128, BN=64, BK=16, 256 threads, 8x4 microtile.
// ---------------------------------------------------------------------------
__global__ __launch_bounds__(256) void proj_gemm_f32(
    const float* __restrict__ X, const float* __restrict__ STE,
    const float* __restrict__ W, const float* __restrict__ bias,
    float* __restrict__ out)
{
  constexpr int BM = 128, BN = 64, BK = 16;
  __shared__ float As[BK][BM + 4];   // [k][m], +4 pad keeps 16B alignment
  __shared__ float Bs[BK][BN];       // [k][n]
  const int tid = threadIdx.x;
  const int r0 = blockIdx.x * BM;
  const int j0 = blockIdx.y * BN;
  const int ty = tid >> 4, tx = tid & 15;

  float acc[8][4];
#pragma unroll
  for (int i = 0; i < 8; ++i)
#pragma unroll
    for (int j = 0; j < 4; ++j) acc[i][j] = 0.f;

  const int bkr = tid >> 4;            // 0..15  (B-tile row)
  const int bjn = (tid & 15) * 4;      // 0..60  (B-tile col)

  for (int kk0 = 0; kk0 < KK; kk0 += BK) {
    // load A tile (128 x 16): 512 float4, 2 per thread, transposed into LDS
#pragma unroll
    for (int pp = 0; pp < 2; ++pp) {
      int p = tid + pp * 256;
      int row = p >> 2;
      int kq = (p & 3) * 4;
      int gk = kk0 + kq;
      const float* src = (gk < 512)
          ? (X + (size_t)(r0 + row) * 512 + gk)
          : (STE + (size_t)(r0 + row) * 512 + (gk - 512));
      float4 a4 = *reinterpret_cast<const float4*>(src);
      As[kq + 0][row] = a4.x;
      As[kq + 1][row] = a4.y;
      As[kq + 2][row] = a4.z;
      As[kq + 3][row] = a4.w;
    }
    // load B tile (16 x 64): 1 float4 per thread
    {
      float4 b4 = *reinterpret_cast<const float4*>(
          W + (size_t)(kk0 + bkr) * 512 + j0 + bjn);
      *reinterpret_cast<float4*>(&Bs[bkr][bjn]) = b4;
    }
    __syncthreads();
#pragma unroll
    for (int kk = 0; kk < BK; ++kk) {
      float4 av0 = *reinterpret_cast<const float4*>(&As[kk][ty * 8]);
      float4 av1 = *reinterpret_cast<const float4*>(&As[kk][ty * 8 + 4]);
      float4 bv  = *reinterpret_cast<const float4*>(&Bs[kk][tx * 4]);
      float a_[8] = {av0.x, av0.y, av0.z, av0.w, av1.x, av1.y, av1.z, av1.w};
      float b_[4] = {bv.x, bv.y, bv.z, bv.w};
#pragma unroll
      for (int i = 0; i < 8; ++i)
#pragma unroll
        for (int j = 0; j < 4; ++j)
          acc[i][j] = fmaf(a_[i], b_[j], acc[i][j]);
    }
    __syncthreads();
  }

  float4 bb = *reinterpret_cast<const float4*>(bias + j0 + tx * 4);
#pragma unroll
  for (int i = 0; i < 8; ++i) {
    int row = r0 + ty * 8 + i;
    float4 o;
    o.x = fmaxf(acc[i][0] + bb.x, 0.f);
    o.y = fmaxf(acc[i][1] + bb.y, 0.f);
    o.z = fmaxf(acc[i][2] + bb.z, 0.f);
    o.w = fmaxf(acc[i][3] + bb.w, 0.f);
    *reinterpret_cast<float4*>(out + (size_t)row * 512 + j0 + tx * 4) = o;
  }
}

// ---------------------------------------------------------------------------
// K2: M[bt,n] = max_s(q[n]·k[sidx[n,s]]) - sum_s(...)/NN     (f32 exact path)
// one block per (bt,n); 4 waves split the 35 sampled dots.
// ---------------------------------------------------------------------------
__global__ __launch_bounds__(256) void sampled_M_kernel(
    const float* __restrict__ q, const float* __restrict__ k,
    const int* __restrict__ sidx, float* __restrict__ Mout)
{
  const int gid = blockIdx.x;        // bt*NN + n
  const int n = gid % NN;
  const int bt = gid / NN;
  const int tid = threadIdx.x;
  const int lane = tid & 63, wid = tid >> 6;
  __shared__ float qs[DD];
  __shared__ float sv[SK];
  for (int c = tid; c < DD; c += 256) qs[c] = q[(size_t)gid * DD + c];
  __syncthreads();
  for (int s = wid; s < SK; s += 4) {
    int m = sidx[n * SK + s];
    const float* krow = k + ((size_t)bt * NN + m) * DD;
    float sum = 0.f;
#pragma unroll
    for (int c = lane; c < DD; c += 64) sum += qs[c] * krow[c];
#pragma unroll
    for (int off = 32; off > 0; off >>= 1) sum += __shfl_down(sum, off);
    if (lane == 0) sv[s] = sum;
  }
  __syncthreads();
  if (tid == 0) {
    float mx = -INFINITY, sm = 0.f;
    for (int s = 0; s < SK; ++s) { mx = fmaxf(mx, sv[s]); sm += sv[s]; }
    Mout[gid] = mx - sm / (float)NN;
  }
}

// ---------------------------------------------------------------------------
// K3: top-35 of M[bt, 0..499] -> idx (stable: ties pick smaller index,
// matching jax.lax.top_k). One block per bt.
// ---------------------------------------------------------------------------
__global__ __launch_bounds__(256) void topk_kernel(
    const float* __restrict__ Mb, int* __restrict__ idxb)
{
  const int bt = blockIdx.x;
  const int tid = threadIdx.x;
  __shared__ float mv[NN];
  __shared__ float rv[256];
  __shared__ int ri[256];
  for (int n = tid; n < NN; n += 256) mv[n] = Mb[(size_t)bt * NN + n];
  __syncthreads();
  for (int it = 0; it < SK; ++it) {
    float bv = -INFINITY; int bi = NN;
    for (int n = tid; n < NN; n += 256) {
      float x = mv[n];
      if (x > bv) { bv = x; bi = n; }   // ascending scan -> first (smallest) idx on ties
    }
    rv[tid] = bv; ri[tid] = bi;
    __syncthreads();
    for (int sft = 128; sft > 0; sft >>= 1) {
      if (tid < sft) {
        float xv = rv[tid + sft]; int xi = ri[tid + sft];
        if (xv > rv[tid] || (xv == rv[tid] && xi < ri[tid])) {
          rv[tid] = xv; ri[tid] = xi;
        }
      }
      __syncthreads();
    }
    if (tid == 0) { idxb[bt * SK + it] = ri[0]; mv[ri[0]] = -INFINITY; }
    __syncthreads();
  }
}

// ---------------------------------------------------------------------------
// K4: for each (bt,u): causal softmax over scores(q[idx_u], k[0..idx_u]) and
// ctx_new[u,:] = attn @ v. One block per (bt,u).
// ---------------------------------------------------------------------------
__global__ __launch_bounds__(256) void attn_sel_kernel(
    const float* __restrict__ q, const float* __restrict__ k,
    const float* __restrict__ v, const int* __restrict__ idxb,
    float* __restrict__ ctxn)
{
  const int blk = blockIdx.x;        // bt*SK + u
  const int u = blk % SK;
  const int bt = blk / SK;
  const int tid = threadIdx.x;
  const int lane = tid & 63, wid = tid >> 6;
  const int qi = idxb[bt * SK + u];  // selected query position (causal bound)
  __shared__ float qs[DD];
  __shared__ float sc[NN];
  __shared__ float wred[4];
  for (int c = tid; c < DD; c += 256)
    qs[c] = q[((size_t)bt * NN + qi) * DD + c];
  __syncthreads();
  const float scale = 0.044194173824159216f;   // 1/sqrt(512)
  for (int m = wid; m <= qi; m += 4) {
    const float* krow = k + ((size_t)bt * NN + m) * DD;
    float sum = 0.f;
#pragma unroll
    for (int c = lane; c < DD; c += 64) sum += qs[c] * krow[c];
#pragma unroll
    for (int off = 32; off > 0; off >>= 1) sum += __shfl_down(sum, off);
    if (lane == 0) sc[m] = sum * scale;
  }
  __syncthreads();
  // row max over [0..qi]
  float lm = -INFINITY;
  for (int m = tid; m <= qi; m += 256) lm = fmaxf(lm, sc[m]);
#pragma unroll
  for (int off = 32; off > 0; off >>= 1) lm = fmaxf(lm, __shfl_down(lm, off));
  if (lane == 0) wred[wid] = lm;
  __syncthreads();
  float mx = fmaxf(fmaxf(wred[0], wred[1]), fmaxf(wred[2], wred[3]));
  __syncthreads();
  // exp + sum
  float ls = 0.f;
  for (int m = tid; m <= qi; m += 256) {
    float e = expf(sc[m] - mx);
    sc[m] = e;
    ls += e;
  }
#pragma unroll
  for (int off = 32; off > 0; off >>= 1) ls += __shfl_down(ls, off);
  if (lane == 0) wred[wid] = ls;
  __syncthreads();
  float inv = 1.f / (wred[0] + wred[1] + wred[2] + wred[3]);
  // PV: thread owns columns tid and tid+256
  float acc0 = 0.f, acc1 = 0.f;
  for (int m = 0; m <= qi; ++m) {
    float w_ = sc[m];
    const float* vrow = v + ((size_t)bt * NN + m) * DD;
    acc0 = fmaf(w_, vrow[tid], acc0);
    acc1 = fmaf(w_, vrow[tid + 256], acc1);
  }
  ctxn[(size_t)blk * DD + tid] = acc0 * inv;
  ctxn[(size_t)blk * DD + tid + 256] = acc1 * inv;
}

// ---------------------------------------------------------------------------
// K5: context = cumsum(v over n); selected rows replaced by ctx_new;
// written transposed as out[b,n,t,d]. One block per bt, 512 threads = D.
// ---------------------------------------------------------------------------
__global__ __launch_bounds__(512) void cumsum_scatter_kernel(
    const float* __restrict__ v, const int* __restrict__ idxb,
    const float* __restrict__ ctxn, float* __restrict__ out)
{
  const int bt = blockIdx.x;
  const int b = bt / T_, t = bt % T_;
  const int tid = threadIdx.x;     // d
  __shared__ int sel[NN];
  for (int n = tid; n < NN; n += 512) sel[n] = -1;
  __syncthreads();
  if (tid < SK) sel[idxb[bt * SK + tid]] = tid;
  __syncthreads();
  float s = 0.f;
  for (int n = 0; n < NN; ++n) {
    s += v[((size_t)bt * NN + n) * DD + tid];
    float o = s;
    int u = sel[n];
    if (u >= 0) o = ctxn[((size_t)bt * SK + u) * DD + tid];
    out[(((size_t)b * NN + n) * T_ + t) * DD + tid] = o;
  }
}

// ---------------------------------------------------------------------------
extern "C" void kernel_launch(void* const* d_in, const int* in_sizes, int n_in,
                              void* d_out, int out_size, void* d_ws, size_t ws_size,
                              hipStream_t stream) {
  const float* X   = (const float*)d_in[0];
  const float* STE = (const float*)d_in[1];
  const float* Wq  = (const float*)d_in[2];
  const float* bq  = (const float*)d_in[3];
  const float* Wk  = (const float*)d_in[4];
  const float* bk  = (const float*)d_in[5];
  const float* Wv  = (const float*)d_in[6];
  const float* bv  = (const float*)d_in[7];
  const int* sidx  = (const int*)d_in[8];
  float* out = (float*)d_out;

  // workspace layout (all 16B aligned): q | k | v | M | idx | ctx_new
  float* q    = (float*)d_ws;                    // 24,576,000 f32
  float* k    = q + (size_t)MROWS * DD;          // 24,576,000 f32
  float* v    = k + (size_t)MROWS * DD;          // 24,576,000 f32
  float* Mb   = v + (size_t)MROWS * DD;          // 48,000 f32
  int*   idxb = (int*)(Mb + MROWS);              // 3,360 i32
  float* ctxn = (float*)(idxb + BT * SK);        // 1,720,320 f32
  (void)ws_size; (void)in_sizes; (void)n_in; (void)out_size;

  dim3 gg(MROWS / 128, DD / 64);
  proj_gemm_f32<<<gg, 256, 0, stream>>>(X, STE, Wq, bq, q);
  proj_gemm_f32<<<gg, 256, 0, stream>>>(X, STE, Wk, bk, k);
  proj_gemm_f32<<<gg, 256, 0, stream>>>(X, STE, Wv, bv, v);
  sampled_M_kernel<<<MROWS, 256, 0, stream>>>(q, k, sidx, Mb);
  topk_kernel<<<BT, 256, 0, stream>>>(Mb, idxb);
  attn_sel_kernel<<<BT * SK, 256, 0, stream>>>(q, k, v, idxb, ctxn);
  cumsum_scatter_kernel<<<BT, 512, 0, stream>>>(v, idxb, ctxn, out);
}

// Round 2
// 1333.503 us; speedup vs baseline: 2.0963x; 2.0963x over previous
//
#include <hip/hip_runtime.h>
#include <math.h>

// Problem constants
#define B_    8
#define T_    12
#define BT    96          // B*T
#define NN    500
#define DD    512
#define KK    1024        // 2*D
#define SK    35          // SAMPLE_K == n_top
#define MROWS 48000       // BT*NN

typedef __bf16 bf16x8 __attribute__((ext_vector_type(8)));
typedef float f32x4 __attribute__((ext_vector_type(4)));
typedef unsigned short u16;
typedef u16 ushort8_t __attribute__((ext_vector_type(8)));
typedef u16 ushort4_t __attribute__((ext_vector_type(4)));

__device__ __forceinline__ u16 bf_hi(float x) {
  __bf16 h = (__bf16)x;
  return __builtin_bit_cast(u16, h);
}
__device__ __forceinline__ float bf_tof(u16 b) {
  unsigned int u = ((unsigned int)b) << 16;
  return __builtin_bit_cast(float, u);
}

// ---------------------------------------------------------------------------
// W -> W^T split into bf16 hi/lo:  Bt[n][k] = W[k][n]
// ---------------------------------------------------------------------------
__global__ __launch_bounds__(256) void convW_kernel(
    const float* __restrict__ W, u16* __restrict__ Bth, u16* __restrict__ Btl)
{
  const int n = blockIdx.x;          // 0..511
  const int k0 = threadIdx.x * 4;    // 0..1020
  float xs[4];
#pragma unroll
  for (int j = 0; j < 4; ++j) xs[j] = W[(size_t)(k0 + j) * 512 + n];
  ushort4_t hi, lo;
#pragma unroll
  for (int j = 0; j < 4; ++j) {
    u16 h = bf_hi(xs[j]);
    hi[j] = h;
    lo[j] = bf_hi(xs[j] - bf_tof(h));
  }
  *(ushort4_t*)(Bth + (size_t)n * 1024 + k0) = hi;
  *(ushort4_t*)(Btl + (size_t)n * 1024 + k0) = lo;
}

// ---------------------------------------------------------------------------
// MFMA projection GEMM: out = relu([X|STE] @ W + bias), C = [48000][512] f32.
// PASSES==3: split-bf16 (AhBh + AhBl + AlBh)  -> used for q, k (accuracy)
// PASSES==1: plain bf16 (AhBh)                -> used for v
// BM=BN=128, BK=32, 256 threads (4 waves, 2x2), 16x16x32 MFMA, 4x4 frags/wave.
// A is reg-staged from f32 X/STE with in-kernel hi/lo conversion.
// 2-bit XOR k-chunk swizzle on LDS tiles (8-way -> 4-way read conflicts).
// ---------------------------------------------------------------------------
template<int PASSES>
__global__ __launch_bounds__(256) void mfma_proj(
    const float* __restrict__ X, const float* __restrict__ STE,
    const u16* __restrict__ Bth, const u16* __restrict__ Btl,
    const float* __restrict__ bias, float* __restrict__ out)
{
  __shared__ u16 lAh[128 * 32];
  __shared__ u16 lAl[128 * 32];
  __shared__ u16 lBh[128 * 32];
  __shared__ u16 lBl[128 * 32];
  const int tid = threadIdx.x;
  const int lane = tid & 63;
  const int wid = tid >> 6;
  const int wm = wid >> 1, wn = wid & 1;
  const int r0 = blockIdx.x * 128;
  const int c0 = blockIdx.y * 128;
  const int fr = lane & 15, fk = lane >> 4;

  f32x4 acc[4][4];
#pragma unroll
  for (int m = 0; m < 4; ++m)
#pragma unroll
    for (int n = 0; n < 4; ++n) acc[m][n] = f32x4{0.f, 0.f, 0.f, 0.f};

  for (int kt = 0; kt < 32; ++kt) {
    const int kk0 = kt * 32;
    // ---- stage tiles (reg-staged, swizzled ds_write) ----
#pragma unroll
    for (int p = 0; p < 2; ++p) {
      const int c = tid + p * 256;          // 0..511 chunk id
      const int row = c >> 2, kc = c & 3;
      const int dst = row * 32 + ((kc ^ (row & 3)) * 8);
      // A: 8 f32 -> bf16 hi/lo
      const int col = kk0 + kc * 8;
      const float* src = (col < 512)
          ? (X + (size_t)(r0 + row) * 512 + col)
          : (STE + (size_t)(r0 + row) * 512 + (col - 512));
      float4 x0 = *(const float4*)src;
      float4 x1 = *(const float4*)(src + 4);
      float xs[8] = {x0.x, x0.y, x0.z, x0.w, x1.x, x1.y, x1.z, x1.w};
      ushort8_t hi, lo;
#pragma unroll
      for (int j = 0; j < 8; ++j) {
        u16 h = bf_hi(xs[j]);
        hi[j] = h;
        if (PASSES == 3) lo[j] = bf_hi(xs[j] - bf_tof(h));
      }
      *(ushort8_t*)&lAh[dst] = hi;
      if (PASSES == 3) *(ushort8_t*)&lAl[dst] = lo;
      // B: already bf16 hi/lo in global (W^T layout [512][1024])
      const size_t gb = (size_t)(c0 + row) * 1024 + kk0 + kc * 8;
      *(ushort8_t*)&lBh[dst] = *(const ushort8_t*)(Bth + gb);
      if (PASSES == 3) *(ushort8_t*)&lBl[dst] = *(const ushort8_t*)(Btl + gb);
    }
    __syncthreads();
    // ---- fragments + MFMA ----
    bf16x8 ah[4], al[4], bh[4], bl[4];
#pragma unroll
    for (int m = 0; m < 4; ++m) {
      const int row = wm * 64 + m * 16 + fr;
      const int off = row * 32 + ((fk ^ (row & 3)) * 8);
      ah[m] = *(const bf16x8*)&lAh[off];
      if (PASSES == 3) al[m] = *(const bf16x8*)&lAl[off];
    }
#pragma unroll
    for (int n = 0; n < 4; ++n) {
      const int row = wn * 64 + n * 16 + fr;
      const int off = row * 32 + ((fk ^ (row & 3)) * 8);
      bh[n] = *(const bf16x8*)&lBh[off];
      if (PASSES == 3) bl[n] = *(const bf16x8*)&lBl[off];
    }
#pragma unroll
    for (int m = 0; m < 4; ++m)
#pragma unroll
      for (int n = 0; n < 4; ++n) {
        acc[m][n] = __builtin_amdgcn_mfma_f32_16x16x32_bf16(
            ah[m], bh[n], acc[m][n], 0, 0, 0);
        if (PASSES == 3) {
          acc[m][n] = __builtin_amdgcn_mfma_f32_16x16x32_bf16(
              ah[m], bl[n], acc[m][n], 0, 0, 0);
          acc[m][n] = __builtin_amdgcn_mfma_f32_16x16x32_bf16(
              al[m], bh[n], acc[m][n], 0, 0, 0);
        }
      }
    __syncthreads();
  }
  // ---- epilogue: bias + relu, f32 store ----
#pragma unroll
  for (int n = 0; n < 4; ++n) {
    const int col = c0 + wn * 64 + n * 16 + fr;
    const float bb = bias[col];
#pragma unroll
    for (int m = 0; m < 4; ++m) {
      const int rowb = r0 + wm * 64 + m * 16 + fk * 4;
#pragma unroll
      for (int r = 0; r < 4; ++r)
        out[(size_t)(rowb + r) * 512 + col] = fmaxf(acc[m][n][r] + bb, 0.f);
    }
  }
}

// ---------------------------------------------------------------------------
// K2: M[bt,n] = max_s(q[n]·k[sidx[n,s]]) - sum_s(...)/NN
// ---------------------------------------------------------------------------
__global__ __launch_bounds__(256) void sampled_M_kernel(
    const float* __restrict__ q, const float* __restrict__ k,
    const int* __restrict__ sidx, float* __restrict__ Mout)
{
  const int gid = blockIdx.x;        // bt*NN + n
  const int n = gid % NN;
  const int bt = gid / NN;
  const int tid = threadIdx.x;
  const int lane = tid & 63, wid = tid >> 6;
  __shared__ float qs[DD];
  __shared__ float sv[SK];
  for (int c = tid; c < DD; c += 256) qs[c] = q[(size_t)gid * DD + c];
  __syncthreads();
  for (int s = wid; s < SK; s += 4) {
    int m = sidx[n * SK + s];
    const float* krow = k + ((size_t)bt * NN + m) * DD;
    float sum = 0.f;
#pragma unroll
    for (int c = lane; c < DD; c += 64) sum += qs[c] * krow[c];
#pragma unroll
    for (int off = 32; off > 0; off >>= 1) sum += __shfl_down(sum, off);
    if (lane == 0) sv[s] = sum;
  }
  __syncthreads();
  if (tid == 0) {
    float mx = -INFINITY, sm = 0.f;
    for (int s = 0; s < SK; ++s) { mx = fmaxf(mx, sv[s]); sm += sv[s]; }
    Mout[gid] = mx - sm / (float)NN;
  }
}

// ---------------------------------------------------------------------------
// K3: top-35 (stable ties -> smaller index)
// ---------------------------------------------------------------------------
__global__ __launch_bounds__(256) void topk_kernel(
    const float* __restrict__ Mb, int* __restrict__ idxb)
{
  const int bt = blockIdx.x;
  const int tid = threadIdx.x;
  __shared__ float mv[NN];
  __shared__ float rv[256];
  __shared__ int ri[256];
  for (int n = tid; n < NN; n += 256) mv[n] = Mb[(size_t)bt * NN + n];
  __syncthreads();
  for (int it = 0; it < SK; ++it) {
    float bv = -INFINITY; int bi = NN;
    for (int n = tid; n < NN; n += 256) {
      float x = mv[n];
      if (x > bv) { bv = x; bi = n; }
    }
    rv[tid] = bv; ri[tid] = bi;
    __syncthreads();
    for (int sft = 128; sft > 0; sft >>= 1) {
      if (tid < sft) {
        float xv = rv[tid + sft]; int xi = ri[tid + sft];
        if (xv > rv[tid] || (xv == rv[tid] && xi < ri[tid])) {
          rv[tid] = xv; ri[tid] = xi;
        }
      }
      __syncthreads();
    }
    if (tid == 0) { idxb[bt * SK + it] = ri[0]; mv[ri[0]] = -INFINITY; }
    __syncthreads();
  }
}

// ---------------------------------------------------------------------------
// K4: causal softmax + PV for selected queries
// ---------------------------------------------------------------------------
__global__ __launch_bounds__(256) void attn_sel_kernel(
    const float* __restrict__ q, const float* __restrict__ k,
    const float* __restrict__ v, const int* __restrict__ idxb,
    float* __restrict__ ctxn)
{
  const int blk = blockIdx.x;        // bt*SK + u
  const int u = blk % SK;
  const int bt = blk / SK;
  const int tid = threadIdx.x;
  const int lane = tid & 63, wid = tid >> 6;
  const int qi = idxb[bt * SK + u];
  __shared__ float qs[DD];
  __shared__ float sc[NN];
  __shared__ float wred[4];
  for (int c = tid; c < DD; c += 256)
    qs[c] = q[((size_t)bt * NN + qi) * DD + c];
  __syncthreads();
  const float scale = 0.044194173824159216f;   // 1/sqrt(512)
  for (int m = wid; m <= qi; m += 4) {
    const float* krow = k + ((size_t)bt * NN + m) * DD;
    float sum = 0.f;
#pragma unroll
    for (int c = lane; c < DD; c += 64) sum += qs[c] * krow[c];
#pragma unroll
    for (int off = 32; off > 0; off >>= 1) sum += __shfl_down(sum, off);
    if (lane == 0) sc[m] = sum * scale;
  }
  __syncthreads();
  float lm = -INFINITY;
  for (int m = tid; m <= qi; m += 256) lm = fmaxf(lm, sc[m]);
#pragma unroll
  for (int off = 32; off > 0; off >>= 1) lm = fmaxf(lm, __shfl_down(lm, off));
  if (lane == 0) wred[wid] = lm;
  __syncthreads();
  float mx = fmaxf(fmaxf(wred[0], wred[1]), fmaxf(wred[2], wred[3]));
  __syncthreads();
  float ls = 0.f;
  for (int m = tid; m <= qi; m += 256) {
    float e = expf(sc[m] - mx);
    sc[m] = e;
    ls += e;
  }
#pragma unroll
  for (int off = 32; off > 0; off >>= 1) ls += __shfl_down(ls, off);
  if (lane == 0) wred[wid] = ls;
  __syncthreads();
  float inv = 1.f / (wred[0] + wred[1] + wred[2] + wred[3]);
  float acc0 = 0.f, acc1 = 0.f;
  for (int m = 0; m <= qi; ++m) {
    float w_ = sc[m];
    const float* vrow = v + ((size_t)bt * NN + m) * DD;
    acc0 = fmaf(w_, vrow[tid], acc0);
    acc1 = fmaf(w_, vrow[tid + 256], acc1);
  }
  ctxn[(size_t)blk * DD + tid] = acc0 * inv;
  ctxn[(size_t)blk * DD + tid + 256] = acc1 * inv;
}

// ---------------------------------------------------------------------------
// K5: causal cumsum + scatter + transposed store
// ---------------------------------------------------------------------------
__global__ __launch_bounds__(512) void cumsum_scatter_kernel(
    const float* __restrict__ v, const int* __restrict__ idxb,
    const float* __restrict__ ctxn, float* __restrict__ out)
{
  const int bt = blockIdx.x;
  const int b = bt / T_, t = bt % T_;
  const int tid = threadIdx.x;     // d
  __shared__ int sel[NN];
  for (int n = tid; n < NN; n += 512) sel[n] = -1;
  __syncthreads();
  if (tid < SK) sel[idxb[bt * SK + tid]] = tid;
  __syncthreads();
  float s = 0.f;
  for (int n = 0; n < NN; ++n) {
    s += v[((size_t)bt * NN + n) * DD + tid];
    float o = s;
    int u = sel[n];
    if (u >= 0) o = ctxn[((size_t)bt * SK + u) * DD + tid];
    out[(((size_t)b * NN + n) * T_ + t) * DD + tid] = o;
  }
}

// ---------------------------------------------------------------------------
extern "C" void kernel_launch(void* const* d_in, const int* in_sizes, int n_in,
                              void* d_out, int out_size, void* d_ws, size_t ws_size,
                              hipStream_t stream) {
  const float* X   = (const float*)d_in[0];
  const float* STE = (const float*)d_in[1];
  const float* Wq  = (const float*)d_in[2];
  const float* bq  = (const float*)d_in[3];
  const float* Wk  = (const float*)d_in[4];
  const float* bk  = (const float*)d_in[5];
  const float* Wv  = (const float*)d_in[6];
  const float* bv  = (const float*)d_in[7];
  const int* sidx  = (const int*)d_in[8];
  float* out = (float*)d_out;

  // workspace layout: q | k | v | M | idx | ctx_new | Bt splits (bf16)
  float* q    = (float*)d_ws;                    // 24,576,000 f32
  float* k    = q + (size_t)MROWS * DD;
  float* v    = k + (size_t)MROWS * DD;
  float* Mb   = v + (size_t)MROWS * DD;          // 48,000 f32
  int*   idxb = (int*)(Mb + MROWS);              // 3,360 i32
  float* ctxn = (float*)(idxb + BT * SK);        // 1,720,320 f32
  u16* Bqh = (u16*)(ctxn + (size_t)BT * SK * DD);
  u16* Bql = Bqh + (size_t)512 * 1024;
  u16* Bkh = Bql + (size_t)512 * 1024;
  u16* Bkl = Bkh + (size_t)512 * 1024;
  u16* Bvh = Bkl + (size_t)512 * 1024;
  u16* Bvl = Bvh + (size_t)512 * 1024;
  (void)ws_size; (void)in_sizes; (void)n_in; (void)out_size;

  convW_kernel<<<512, 256, 0, stream>>>(Wq, Bqh, Bql);
  convW_kernel<<<512, 256, 0, stream>>>(Wk, Bkh, Bkl);
  convW_kernel<<<512, 256, 0, stream>>>(Wv, Bvh, Bvl);

  dim3 gg(MROWS / 128, 4);
  mfma_proj<3><<<gg, 256, 0, stream>>>(X, STE, Bqh, Bql, bq, q);
  mfma_proj<3><<<gg, 256, 0, stream>>>(X, STE, Bkh, Bkl, bk, k);
  mfma_proj<1><<<gg, 256, 0, stream>>>(X, STE, Bvh, Bvl, bv, v);

  sampled_M_kernel<<<MROWS, 256, 0, stream>>>(q, k, sidx, Mb);
  topk_kernel<<<BT, 256, 0, stream>>>(Mb, idxb);
  attn_sel_kernel<<<BT * SK, 256, 0, stream>>>(q, k, v, idxb, ctxn);
  cumsum_scatter_kernel<<<BT, 512, 0, stream>>>(v, idxb, ctxn, out);
}